// Round 10
// baseline (1176.521 us; speedup 1.0000x reference)
//
#include <hip/hip_runtime.h>
#include <math.h>

// FusionEncoder: E=1024, F=4096, N=64 docs, L=2 layers, fp32.
// R10: multi-kernel + split-K with IN-KERNEL last-block tail-reduce.
// R9's i64 atomics = 78us GEMMs (64MB RMW traffic). Here: fp32 partial slots
// (deterministic fixed-order sum by the LAST block per column-block, selected
// via an int arrival counter -- only the counter is racy, never the floats).
// Kills all 8 reduce dispatches; 18 dispatch units total.

#define EDIM 1024
#define FDIM 4096

// ---------------- block-wide sum over 256 threads (4 waves) ----------------
__device__ __forceinline__ float block_sum256(float v) {
  __shared__ float lds[4];
  #pragma unroll
  for (int off = 32; off; off >>= 1) v += __shfl_down(v, off);
  const int wid  = threadIdx.x >> 6;
  const int lane = threadIdx.x & 63;
  __syncthreads();
  if (lane == 0) lds[wid] = v;
  __syncthreads();
  return lds[0] + lds[1] + lds[2] + lds[3];
}

#define FMA4(ACC, S, W4) \
  ACC.x = fmaf(S, W4.x, ACC.x); ACC.y = fmaf(S, W4.y, ACC.y); \
  ACC.z = fmaf(S, W4.z, ACC.z); ACC.w = fmaf(S, W4.w, ACC.w);

// ---- skinny GEMM 64x64 tile + LAST-BLOCK TAIL REDUCE -----------------------
// grid = (Nout/64, S); block (bx,by) computes K-slice [by*Kt, by*Kt+Kt) of
// columns [bx*64, bx*64+64), writes partial slot by, bumps cnt[bx]; the last
// arrival re-reads slots 0..S-1 in FIXED order (deterministic), applies the
// epilogue, writes 'out'.
// MODE_A: 0 plain float A (lda); 1 concat(query,doc).
// EPI: 0 = sum+bias; 1 = relu(sum+bias); 2 = sum+bias+res (pre-LN).
template<int MODE_A, int EPI>
__global__ __launch_bounds__(256)
void gemm_k(const float* __restrict__ Af, int lda,
            const float* __restrict__ qv, const float* __restrict__ doc,
            const float* __restrict__ W, int ldw,
            const float* __restrict__ bias, const float* __restrict__ res,
            float* __restrict__ P, float* __restrict__ out,
            int Nout, int Kt, int S, int* __restrict__ cnt)
{
  __shared__ float As[64 * 68];
  __shared__ float Ws[64 * 68];
  __shared__ int amLast;
  const int t   = threadIdx.x;
  const int cgi = t & 15;
  const int r0  = (t >> 4) * 4;
  const int jb  = blockIdx.x * 64;
  const int jc  = jb + cgi * 4;
  const int kb  = blockIdx.y * Kt;

  float4 acc[4];
  #pragma unroll
  for (int i = 0; i < 4; ++i) acc[i] = make_float4(0.f, 0.f, 0.f, 0.f);

  for (int k0 = kb; k0 < kb + Kt; k0 += 64) {
    __syncthreads();
    #pragma unroll
    for (int it = 0; it < 4; ++it) {               // stage A[0..63][k0+0..63]
      const int pi  = t + it * 256;
      const int row = pi >> 4;
      const int c4  = (pi & 15) * 4;
      const int k   = k0 + c4;
      float4 val;
      if (MODE_A == 1)
        val = (k < EDIM) ? *(const float4*)(qv + k)
                         : *(const float4*)(doc + (size_t)row * EDIM + (k - EDIM));
      else
        val = *(const float4*)(Af + (size_t)row * lda + k);
      *(float4*)(As + row * 68 + c4) = val;
    }
    #pragma unroll
    for (int it = 0; it < 4; ++it) {               // stage W[k0+0..63][jb+0..63]
      const int pi  = t + it * 256;
      const int row = pi >> 4;
      const int c4  = (pi & 15) * 4;
      *(float4*)(Ws + row * 68 + c4) =
          *(const float4*)(W + (size_t)(k0 + row) * ldw + jb + c4);
    }
    __syncthreads();
    #pragma unroll 4
    for (int kk4 = 0; kk4 < 64; kk4 += 4) {
      const float4 a0 = *(const float4*)(As + (r0 + 0) * 68 + kk4);
      const float4 a1 = *(const float4*)(As + (r0 + 1) * 68 + kk4);
      const float4 a2 = *(const float4*)(As + (r0 + 2) * 68 + kk4);
      const float4 a3 = *(const float4*)(As + (r0 + 3) * 68 + kk4);
      const float4 w0 = *(const float4*)(Ws + (kk4 + 0) * 68 + cgi * 4);
      const float4 w1 = *(const float4*)(Ws + (kk4 + 1) * 68 + cgi * 4);
      const float4 w2 = *(const float4*)(Ws + (kk4 + 2) * 68 + cgi * 4);
      const float4 w3 = *(const float4*)(Ws + (kk4 + 3) * 68 + cgi * 4);
      FMA4(acc[0], a0.x, w0) FMA4(acc[0], a0.y, w1) FMA4(acc[0], a0.z, w2) FMA4(acc[0], a0.w, w3)
      FMA4(acc[1], a1.x, w0) FMA4(acc[1], a1.y, w1) FMA4(acc[1], a1.z, w2) FMA4(acc[1], a1.w, w3)
      FMA4(acc[2], a2.x, w0) FMA4(acc[2], a2.y, w1) FMA4(acc[2], a2.z, w2) FMA4(acc[2], a2.w, w3)
      FMA4(acc[3], a3.x, w0) FMA4(acc[3], a3.y, w1) FMA4(acc[3], a3.z, w2) FMA4(acc[3], a3.w, w3)
    }
  }

  // write my partial slot
  float* myP = P + (size_t)blockIdx.y * 64 * Nout;
  #pragma unroll
  for (int i = 0; i < 4; ++i)
    *(float4*)(myP + (size_t)(r0 + i) * Nout + jc) = acc[i];

  // arrival protocol
  __threadfence();
  __syncthreads();
  if (t == 0) {
    const int prev = __hip_atomic_fetch_add(cnt + blockIdx.x, 1,
                        __ATOMIC_ACQ_REL, __HIP_MEMORY_SCOPE_AGENT);
    amLast = (prev == S - 1);
  }
  __syncthreads();
  if (!amLast) return;
  __builtin_amdgcn_fence(__ATOMIC_ACQUIRE, "agent");

  // fixed-order deterministic sum over slots + epilogue
  #pragma unroll
  for (int i = 0; i < 4; ++i) {
    const int row = r0 + i;
    float4 v = make_float4(0.f, 0.f, 0.f, 0.f);
    for (int s = 0; s < S; ++s) {
      const float4 pp = *(const float4*)(P + ((size_t)s * 64 + row) * Nout + jc);
      v.x += pp.x; v.y += pp.y; v.z += pp.z; v.w += pp.w;
    }
    const float4 b4 = *(const float4*)(bias + jc);
    v.x += b4.x; v.y += b4.y; v.z += b4.z; v.w += b4.w;
    if (EPI == 1) {
      v.x = fmaxf(v.x, 0.f); v.y = fmaxf(v.y, 0.f);
      v.z = fmaxf(v.z, 0.f); v.w = fmaxf(v.w, 0.f);
    } else if (EPI == 2) {
      const float4 r4 = *(const float4*)(res + (size_t)row * EDIM + jc);
      v.x += r4.x; v.y += r4.y; v.z += r4.z; v.w += r4.w;
    }
    *(float4*)(out + (size_t)row * Nout + jc) = v;
  }
}

// ---- LayerNorm over rows of pre[64][1024] -> out ---------------------------
__global__ __launch_bounds__(256)
void ln_k(const float* __restrict__ pre, const float* __restrict__ gam,
          const float* __restrict__ bet, float* __restrict__ outp)
{
  const int row = blockIdx.x;
  const int c   = threadIdx.x * 4;
  float4 v = *(const float4*)(pre + (size_t)row * EDIM + c);
  const float mean = block_sum256(v.x + v.y + v.z + v.w) * (1.f / 1024.f);
  const float dx = v.x - mean, dy = v.y - mean, dz = v.z - mean, dw = v.w - mean;
  const float var = block_sum256(dx * dx + dy * dy + dz * dz + dw * dw) * (1.f / 1024.f);
  const float inv = 1.f / sqrtf(var + 1e-5f);
  const float4 g4 = *(const float4*)(gam + c);
  const float4 l4 = *(const float4*)(bet + c);
  float4 o;
  o.x = dx * inv * g4.x + l4.x; o.y = dy * inv * g4.y + l4.y;
  o.z = dz * inv * g4.z + l4.z; o.w = dw * inv * g4.w + l4.w;
  *(float4*)(outp + (size_t)row * EDIM + c) = o;
}

// ---- logits[row] = a[row,:] . Wa2 + ba2 ; 64 blocks ------------------------
__global__ __launch_bounds__(256)
void logits_k(const float* __restrict__ a, const float* __restrict__ Wa2,
              const float* __restrict__ ba2, float* __restrict__ logits)
{
  const int row = blockIdx.x;
  const int t   = threadIdx.x;
  float dot = 0.f;
  #pragma unroll
  for (int i = 0; i < 4; ++i) {
    const int col = (t + i * 256) * 4;
    const float4 v  = *(const float4*)(a + (size_t)row * FDIM + col);
    const float4 w2 = *(const float4*)(Wa2 + col);
    dot = fmaf(v.x, w2.x, fmaf(v.y, w2.y, fmaf(v.z, w2.z, fmaf(v.w, w2.w, dot))));
  }
  const float s = block_sum256(dot);
  if (t == 0) logits[row] = s + ba2[0];
}

// ---- softmax over 64 + weighted pool; block 0 writes w ---------------------
__global__ __launch_bounds__(256)
void pool_k(const float* __restrict__ logits, const float* __restrict__ x,
            float* __restrict__ fused, float* __restrict__ w_out)
{
  __shared__ float llv[64];
  __shared__ float wl[64];
  const int t = threadIdx.x;
  if (t < 64) llv[t] = logits[t];
  __syncthreads();
  float m = -1e30f;
  for (int i = 0; i < 64; ++i) m = fmaxf(m, llv[i]);
  float den = 0.f;
  for (int i = 0; i < 64; ++i) den += expf(llv[i] - m);
  if (t < 64) wl[t] = expf(llv[t] - m) / den;
  __syncthreads();
  const int j = blockIdx.x * 256 + t;
  float acc = 0.f;
  for (int i = 0; i < 64; ++i) acc = fmaf(wl[i], x[(size_t)i * EDIM + j], acc);
  fused[j] = acc;
  if (blockIdx.x == 0 && t < 64) w_out[t] = wl[t];
}

// ---- GEMV + tail: out = epi(vec @ Wbig + bias) -----------------------------
// grid = (4096/256, S); Kt per split; partial Pg[s][4096]; cnt[16].
template<int KT, int RELU>
__global__ __launch_bounds__(256)
void gemv_k(const float* __restrict__ vec, const float* __restrict__ Wb,
            const float* __restrict__ bias, float* __restrict__ Pg,
            float* __restrict__ out, int S, int* __restrict__ cnt)
{
  __shared__ float vl[KT];
  __shared__ int amLast;
  const int t  = threadIdx.x;
  const int k0 = blockIdx.y * KT;
  if (t < KT) vl[t] = vec[k0 + t];
  __syncthreads();
  const int col = blockIdx.x * 256 + t;
  const float* wp = Wb + (size_t)k0 * FDIM + col;
  float acc = 0.f;
  #pragma unroll 16
  for (int kk = 0; kk < KT; ++kk) acc = fmaf(vl[kk], wp[(size_t)kk * FDIM], acc);
  Pg[(size_t)blockIdx.y * FDIM + col] = acc;

  __threadfence();
  __syncthreads();
  if (t == 0) {
    const int prev = __hip_atomic_fetch_add(cnt + blockIdx.x, 1,
                        __ATOMIC_ACQ_REL, __HIP_MEMORY_SCOPE_AGENT);
    amLast = (prev == S - 1);
  }
  __syncthreads();
  if (!amLast) return;
  __builtin_amdgcn_fence(__ATOMIC_ACQUIRE, "agent");
  float v = 0.f;
  for (int s = 0; s < S; ++s) v += Pg[(size_t)s * FDIM + col];
  v += bias[col];
  if (RELU) v = fmaxf(v, 0.f);
  out[col] = v;
}

// ---------------------------------------------------------------------------
extern "C" void kernel_launch(void* const* d_in, const int* in_sizes, int n_in,
                              void* d_out, int out_size, void* d_ws, size_t ws_size,
                              hipStream_t stream) {
  (void)in_sizes; (void)n_in; (void)out_size; (void)ws_size;
  const float* q    = (const float*)d_in[0];
  const float* doc  = (const float*)d_in[1];
  const float* Wp   = (const float*)d_in[2];
  const float* bp   = (const float*)d_in[3];
  const float* Wqkv = (const float*)d_in[4];
  const float* bqkv = (const float*)d_in[5];
  const float* Wo   = (const float*)d_in[6];
  const float* bo   = (const float*)d_in[7];
  const float* ln1g = (const float*)d_in[8];
  const float* ln1b = (const float*)d_in[9];
  const float* ln2g = (const float*)d_in[10];
  const float* ln2b = (const float*)d_in[11];
  const float* W1   = (const float*)d_in[12];
  const float* b1   = (const float*)d_in[13];
  const float* W2   = (const float*)d_in[14];
  const float* b2   = (const float*)d_in[15];
  const float* Wa1  = (const float*)d_in[16];
  const float* ba1  = (const float*)d_in[17];
  const float* Wa2  = (const float*)d_in[18];
  const float* ba2  = (const float*)d_in[19];
  const float* Wf1  = (const float*)d_in[20];
  const float* bf1  = (const float*)d_in[21];
  const float* Wf2  = (const float*)d_in[22];
  const float* bf2  = (const float*)d_in[23];
  float* out = (float*)d_out;
  float* ws  = (float*)d_ws;

  // workspace layout (floats)
  float* x      = ws;                  // 64x1024
  float* vbuf   = ws + 65536;          // 64x1024
  float* xpre   = ws + 131072;         // 64x1024 (pre-LN)
  float* h      = ws + 196608;         // 64x4096
  float* a      = ws + 458752;         // 64x4096
  float* fused  = ws + 720896;         // 1024
  float* g      = ws + 721920;         // 4096
  float* logit  = ws + 726016;         // 64 (+pad)
  float* P      = ws + 726272;         // up to 16 x 64 x 4096 = 4M floats
  int*   cnt    = (int*)(ws + 4920576);// 1024 ints of counters

  // counter offsets per gemm dispatch (distinct regions)
  int* c_proj = cnt;        // 16
  int* c_v0   = cnt + 16;   // 16
  int* c_at0  = cnt + 32;   // 16
  int* c_f10  = cnt + 48;   // 64
  int* c_f20  = cnt + 112;  // 16
  int* c_v1   = cnt + 128;  // 16
  int* c_at1  = cnt + 144;  // 16
  int* c_f11  = cnt + 160;  // 64
  int* c_f21  = cnt + 224;  // 16
  int* c_wa1  = cnt + 240;  // 64
  int* c_gv1  = cnt + 304;  // 16
  int* c_gv2  = cnt + 320;  // 16

  const dim3 blk(256);
  (void)hipMemsetAsync(cnt, 0, 4096, stream);

  // proj: x = concat(q,doc)@Wp + bp    (grid 16x32, Kt=64, K=2048)
  gemm_k<1,0><<<dim3(16,32), blk, 0, stream>>>(nullptr, 0, q, doc, Wp, EDIM,
      bp, nullptr, P, x, EDIM, 64, 32, c_proj);

  for (int l = 0; l < 2; ++l) {
    const float* Wv  = Wqkv + (size_t)l * EDIM * 3 * EDIM + 2 * EDIM;
    const float* bv  = bqkv + l * 3 * EDIM + 2 * EDIM;
    const float* Wol = Wo + (size_t)l * EDIM * EDIM;
    const float* W1l = W1 + (size_t)l * EDIM * FDIM;
    const float* W2l = W2 + (size_t)l * FDIM * EDIM;
    int* cv = l ? c_v1 : c_v0;
    int* ca = l ? c_at1 : c_at0;
    int* c1 = l ? c_f11 : c_f10;
    int* c2 = l ? c_f21 : c_f20;

    // v = x@Wv + bv      (grid 16x16, Kt=64)
    gemm_k<0,0><<<dim3(16,16), blk, 0, stream>>>(x, EDIM, nullptr, nullptr,
        Wv, 3 * EDIM, bv, nullptr, P, vbuf, EDIM, 64, 16, cv);

    // xpre = x + v@Wo + bo   (grid 16x16, Kt=64)
    gemm_k<0,2><<<dim3(16,16), blk, 0, stream>>>(vbuf, EDIM, nullptr, nullptr,
        Wol, EDIM, bo + l * EDIM, x, P, xpre, EDIM, 64, 16, ca);
    ln_k<<<64, blk, 0, stream>>>(xpre, ln1g + l * EDIM, ln1b + l * EDIM, x);

    // h = relu(x@W1 + b1)    (grid 64x16, Kt=64)
    gemm_k<0,1><<<dim3(64,16), blk, 0, stream>>>(x, EDIM, nullptr, nullptr,
        W1l, FDIM, b1 + (size_t)l * FDIM, nullptr, P, h, FDIM, 64, 16, c1);

    // xpre = x + h@W2 + b2   (grid 16x32, Kt=128, K=4096)
    gemm_k<0,2><<<dim3(16,32), blk, 0, stream>>>(h, FDIM, nullptr, nullptr,
        W2l, EDIM, b2 + l * EDIM, x, P, xpre, EDIM, 128, 32, c2);
    ln_k<<<64, blk, 0, stream>>>(xpre, ln2g + l * EDIM, ln2b + l * EDIM, x);
  }

  // a = relu(x@Wa1 + ba1)    (grid 64x16, Kt=64)
  gemm_k<0,1><<<dim3(64,16), blk, 0, stream>>>(x, EDIM, nullptr, nullptr,
      Wa1, FDIM, ba1, nullptr, P, a, FDIM, 64, 16, c_wa1);

  logits_k<<<64, blk, 0, stream>>>(a, Wa2, ba2, logit);
  pool_k<<<4, blk, 0, stream>>>(logit, x, fused, out + FDIM);

  // g = relu(fused@Wf1 + bf1)   (grid 16x32, Kt=32)
  gemv_k<32,1><<<dim3(16,32), blk, 0, stream>>>(fused, Wf1, bf1, P, g, 32, c_gv1);
  // out = g@Wf2 + bf2           (grid 16x64, Kt=64)
  gemv_k<64,0><<<dim3(16,64), blk, 0, stream>>>(g, Wf2, bf2, P, out, 64, c_gv2);
}

// Round 11
// 279.284 us; speedup vs baseline: 4.2126x; 4.2126x over previous
//
#include <hip/hip_runtime.h>
#include <math.h>

// FusionEncoder: E=1024, F=4096, N=64 docs, L=2 layers, fp32.
// R11: fence-free multi-kernel. Consumers sum producer split-K partials in
// FIXED ORDER during their A-stage (deterministic; kernel boundary = the only
// sync). No atomics, no fences, no memsets anywhere -- R8/R9/R10 showed
// per-block agent-scope sync costs ~0.1-0.4us serialized chip-wide.
// 19 dispatches vs R3's 26.

#define EDIM 1024
#define FDIM 4096

__device__ __forceinline__ float block_sum256(float v) {
  __shared__ float lds[4];
  #pragma unroll
  for (int off = 32; off; off >>= 1) v += __shfl_down(v, off);
  const int wid  = threadIdx.x >> 6;
  const int lane = threadIdx.x & 63;
  __syncthreads();
  if (lane == 0) lds[wid] = v;
  __syncthreads();
  return lds[0] + lds[1] + lds[2] + lds[3];
}

#define FMA4(ACC, S, W4) \
  ACC.x = fmaf(S, W4.x, ACC.x); ACC.y = fmaf(S, W4.y, ACC.y); \
  ACC.z = fmaf(S, W4.z, ACC.z); ACC.w = fmaf(S, W4.w, ACC.w);
#define ADD4(A, B) { A.x += B.x; A.y += B.y; A.z += B.z; A.w += B.w; }

// ---- skinny GEMM 64x64 tile; A & W staged in LDS; writes partial slot ------
// MODE_A: 0 = plain float A; 1 = concat(query,doc);
//         2 = psum(Ap slots 0..Sa-1) + abias;  3 = relu(psum + abias).
template<int MODE_A>
__global__ __launch_bounds__(256)
void gemm_k(const float* __restrict__ Af,
            const float* __restrict__ Ap, int Sa, int lda,
            const float* __restrict__ abias,
            const float* __restrict__ qv, const float* __restrict__ doc,
            const float* __restrict__ W, int ldw,
            float* __restrict__ Pout, int Nout, int Kt)
{
  __shared__ float As[64 * 68];
  __shared__ float Ws[64 * 68];
  const int t   = threadIdx.x;
  const int cgi = t & 15;
  const int r0  = (t >> 4) * 4;
  const int jb  = blockIdx.x * 64;
  const int jc  = jb + cgi * 4;
  const int kb  = blockIdx.y * Kt;

  float4 acc[4];
  #pragma unroll
  for (int i = 0; i < 4; ++i) acc[i] = make_float4(0.f, 0.f, 0.f, 0.f);

  for (int k0 = kb; k0 < kb + Kt; k0 += 64) {
    __syncthreads();
    #pragma unroll
    for (int it = 0; it < 4; ++it) {               // stage A[0..63][k0+0..63]
      const int pi  = t + it * 256;
      const int row = pi >> 4;
      const int c4  = (pi & 15) * 4;
      const int k   = k0 + c4;
      float4 val;
      if (MODE_A == 0) {
        val = *(const float4*)(Af + (size_t)row * lda + k);
      } else if (MODE_A == 1) {
        val = (k < EDIM) ? *(const float4*)(qv + k)
                         : *(const float4*)(doc + (size_t)row * EDIM + (k - EDIM));
      } else {
        val = *(const float4*)(abias + k);
        for (int s = 0; s < Sa; ++s) {
          const float4 pp = *(const float4*)(Ap + ((size_t)(s * 64 + row)) * lda + k);
          ADD4(val, pp)
        }
        if (MODE_A == 3) {
          val.x = fmaxf(val.x, 0.f); val.y = fmaxf(val.y, 0.f);
          val.z = fmaxf(val.z, 0.f); val.w = fmaxf(val.w, 0.f);
        }
      }
      *(float4*)(As + row * 68 + c4) = val;
    }
    #pragma unroll
    for (int it = 0; it < 4; ++it) {               // stage W[k0+0..63][jb+0..63]
      const int pi  = t + it * 256;
      const int row = pi >> 4;
      const int c4  = (pi & 15) * 4;
      *(float4*)(Ws + row * 68 + c4) =
          *(const float4*)(W + (size_t)(k0 + row) * ldw + jb + c4);
    }
    __syncthreads();
    #pragma unroll 4
    for (int kk4 = 0; kk4 < 64; kk4 += 4) {
      const float4 a0 = *(const float4*)(As + (r0 + 0) * 68 + kk4);
      const float4 a1 = *(const float4*)(As + (r0 + 1) * 68 + kk4);
      const float4 a2 = *(const float4*)(As + (r0 + 2) * 68 + kk4);
      const float4 a3 = *(const float4*)(As + (r0 + 3) * 68 + kk4);
      const float4 w0 = *(const float4*)(Ws + (kk4 + 0) * 68 + cgi * 4);
      const float4 w1 = *(const float4*)(Ws + (kk4 + 1) * 68 + cgi * 4);
      const float4 w2 = *(const float4*)(Ws + (kk4 + 2) * 68 + cgi * 4);
      const float4 w3 = *(const float4*)(Ws + (kk4 + 3) * 68 + cgi * 4);
      FMA4(acc[0], a0.x, w0) FMA4(acc[0], a0.y, w1) FMA4(acc[0], a0.z, w2) FMA4(acc[0], a0.w, w3)
      FMA4(acc[1], a1.x, w0) FMA4(acc[1], a1.y, w1) FMA4(acc[1], a1.z, w2) FMA4(acc[1], a1.w, w3)
      FMA4(acc[2], a2.x, w0) FMA4(acc[2], a2.y, w1) FMA4(acc[2], a2.z, w2) FMA4(acc[2], a2.w, w3)
      FMA4(acc[3], a3.x, w0) FMA4(acc[3], a3.y, w1) FMA4(acc[3], a3.z, w2) FMA4(acc[3], a3.w, w3)
    }
  }
  float* o = Pout + (size_t)blockIdx.y * 64 * Nout;
  #pragma unroll
  for (int i = 0; i < 4; ++i)
    *(float4*)(o + (size_t)(r0 + i) * Nout + jc) = acc[i];
}

// ---- LayerNorm: out = LN(psum(PA)+abias + res); res = float or psum+rbias --
template<int RESPSUM>
__global__ __launch_bounds__(256)
void ln_k(const float* __restrict__ PA, int Sa, const float* __restrict__ abias,
          const float* __restrict__ resf,
          const float* __restrict__ resP, int Sr, const float* __restrict__ rbias,
          const float* __restrict__ gam, const float* __restrict__ bet,
          float* __restrict__ outp)
{
  const int row = blockIdx.x;
  const int c   = threadIdx.x * 4;
  float4 v = *(const float4*)(abias + c);
  for (int s = 0; s < Sa; ++s) {
    const float4 pp = *(const float4*)(PA + ((size_t)(s * 64 + row)) * EDIM + c);
    ADD4(v, pp)
  }
  if (RESPSUM) {
    float4 r = *(const float4*)(rbias + c);
    for (int s = 0; s < Sr; ++s) {
      const float4 pp = *(const float4*)(resP + ((size_t)(s * 64 + row)) * EDIM + c);
      ADD4(r, pp)
    }
    ADD4(v, r)
  } else {
    const float4 r4 = *(const float4*)(resf + (size_t)row * EDIM + c);
    ADD4(v, r4)
  }
  const float mean = block_sum256(v.x + v.y + v.z + v.w) * (1.f / 1024.f);
  const float dx = v.x - mean, dy = v.y - mean, dz = v.z - mean, dw = v.w - mean;
  const float var = block_sum256(dx * dx + dy * dy + dz * dz + dw * dw) * (1.f / 1024.f);
  const float inv = 1.f / sqrtf(var + 1e-5f);
  const float4 g4 = *(const float4*)(gam + c);
  const float4 l4 = *(const float4*)(bet + c);
  float4 o;
  o.x = dx * inv * g4.x + l4.x; o.y = dy * inv * g4.y + l4.y;
  o.z = dz * inv * g4.z + l4.z; o.w = dw * inv * g4.w + l4.w;
  *(float4*)(outp + (size_t)row * EDIM + c) = o;
}

// ---- logits[row] = relu(psum(Pa)+ba1) . Wa2 + ba2 ; 64 blocks --------------
__global__ __launch_bounds__(256)
void logits_k(const float* __restrict__ Pa, int Sa, const float* __restrict__ ba1,
              const float* __restrict__ Wa2, const float* __restrict__ ba2,
              float* __restrict__ logits)
{
  const int row = blockIdx.x;
  const int t   = threadIdx.x;
  float dot = 0.f;
  #pragma unroll
  for (int i = 0; i < 4; ++i) {
    const int col = (t + i * 256) * 4;
    float4 v = *(const float4*)(ba1 + col);
    for (int s = 0; s < Sa; ++s) {
      const float4 pp = *(const float4*)(Pa + ((size_t)(s * 64 + row)) * FDIM + col);
      ADD4(v, pp)
    }
    v.x = fmaxf(v.x, 0.f); v.y = fmaxf(v.y, 0.f);
    v.z = fmaxf(v.z, 0.f); v.w = fmaxf(v.w, 0.f);
    const float4 w2 = *(const float4*)(Wa2 + col);
    dot = fmaf(v.x, w2.x, fmaf(v.y, w2.y, fmaf(v.z, w2.z, fmaf(v.w, w2.w, dot))));
  }
  const float s = block_sum256(dot);
  if (t == 0) logits[row] = s + ba2[0];
}

// ---- softmax over 64 + weighted pool; block 0 writes w ---------------------
__global__ __launch_bounds__(256)
void pool_k(const float* __restrict__ logits, const float* __restrict__ x,
            float* __restrict__ fused, float* __restrict__ w_out)
{
  __shared__ float llv[64];
  __shared__ float wl[64];
  const int t = threadIdx.x;
  if (t < 64) llv[t] = logits[t];
  __syncthreads();
  float m = -1e30f;
  for (int i = 0; i < 64; ++i) m = fmaxf(m, llv[i]);
  float den = 0.f;
  for (int i = 0; i < 64; ++i) den += expf(llv[i] - m);
  if (t < 64) wl[t] = expf(llv[t] - m) / den;
  __syncthreads();
  const int j = blockIdx.x * 256 + t;
  float acc = 0.f;
  for (int i = 0; i < 64; ++i) acc = fmaf(wl[i], x[(size_t)i * EDIM + j], acc);
  fused[j] = acc;
  if (blockIdx.x == 0 && t < 64) w_out[t] = wl[t];
}

// ---- gemv1: P_g[by] = fused[k-slice] @ Wf1 ; float4/lane; grid (4,32) ------
__global__ __launch_bounds__(256)
void gemv1_k(const float* __restrict__ vec, const float* __restrict__ W,
             float* __restrict__ Pg)
{
  __shared__ float vl[32];
  const int t  = threadIdx.x;
  const int k0 = blockIdx.y * 32;
  if (t < 32) vl[t] = vec[k0 + t];
  __syncthreads();
  const int col = blockIdx.x * 1024 + t * 4;
  const float* wp = W + (size_t)k0 * FDIM + col;
  float4 acc = make_float4(0.f, 0.f, 0.f, 0.f);
  #pragma unroll 8
  for (int kk = 0; kk < 32; ++kk) {
    const float4 w = *(const float4*)(wp + (size_t)kk * FDIM);
    FMA4(acc, vl[kk], w)
  }
  *(float4*)(Pg + (size_t)blockIdx.y * FDIM + col) = acc;
}

// ---- gemv2: P_o[by] = relu(psum(Pg)+bf1)[k-slice] @ Wf2 ; grid (4,64) ------
__global__ __launch_bounds__(256)
void gemv2_k(const float* __restrict__ Pg, int Sg, const float* __restrict__ bf1,
             const float* __restrict__ W, float* __restrict__ Po)
{
  __shared__ float vl[64];
  const int t  = threadIdx.x;
  const int k0 = blockIdx.y * 64;
  if (t < 64) {
    float v = bf1[k0 + t];
    for (int s = 0; s < Sg; ++s) v += Pg[(size_t)s * FDIM + k0 + t];
    vl[t] = fmaxf(v, 0.f);
  }
  __syncthreads();
  const int col = blockIdx.x * 1024 + t * 4;
  const float* wp = W + (size_t)k0 * FDIM + col;
  float4 acc = make_float4(0.f, 0.f, 0.f, 0.f);
  #pragma unroll 8
  for (int kk = 0; kk < 64; ++kk) {
    const float4 w = *(const float4*)(wp + (size_t)kk * FDIM);
    FMA4(acc, vl[kk], w)
  }
  *(float4*)(Po + (size_t)blockIdx.y * FDIM + col) = acc;
}

// ---- final: out = psum(Po) + bf2 ; 4 blocks --------------------------------
__global__ __launch_bounds__(256)
void final_k(const float* __restrict__ Po, int So, const float* __restrict__ bf2,
             float* __restrict__ out)
{
  const int col = blockIdx.x * 1024 + threadIdx.x * 4;
  float4 v = *(const float4*)(bf2 + col);
  for (int s = 0; s < So; ++s) {
    const float4 pp = *(const float4*)(Po + (size_t)s * FDIM + col);
    ADD4(v, pp)
  }
  *(float4*)(out + col) = v;
}

// ---------------------------------------------------------------------------
extern "C" void kernel_launch(void* const* d_in, const int* in_sizes, int n_in,
                              void* d_out, int out_size, void* d_ws, size_t ws_size,
                              hipStream_t stream) {
  (void)in_sizes; (void)n_in; (void)out_size; (void)ws_size;
  const float* q    = (const float*)d_in[0];
  const float* doc  = (const float*)d_in[1];
  const float* Wp   = (const float*)d_in[2];
  const float* bp   = (const float*)d_in[3];
  const float* Wqkv = (const float*)d_in[4];
  const float* bqkv = (const float*)d_in[5];
  const float* Wo   = (const float*)d_in[6];
  const float* bo   = (const float*)d_in[7];
  const float* ln1g = (const float*)d_in[8];
  const float* ln1b = (const float*)d_in[9];
  const float* ln2g = (const float*)d_in[10];
  const float* ln2b = (const float*)d_in[11];
  const float* W1   = (const float*)d_in[12];
  const float* b1   = (const float*)d_in[13];
  const float* W2   = (const float*)d_in[14];
  const float* b2   = (const float*)d_in[15];
  const float* Wa1  = (const float*)d_in[16];
  const float* ba1  = (const float*)d_in[17];
  const float* Wa2  = (const float*)d_in[18];
  const float* ba2  = (const float*)d_in[19];
  const float* Wf1  = (const float*)d_in[20];
  const float* bf1  = (const float*)d_in[21];
  const float* Wf2  = (const float*)d_in[22];
  const float* bf2  = (const float*)d_in[23];
  float* out = (float*)d_out;
  float* ws  = (float*)d_ws;

  // workspace layout (floats)
  float* x1    = ws;                  // 64x1024 (post-LN1 layer0)
  float* x2    = ws + 65536;          // 64x1024
  float* x3    = ws + 131072;         // 64x1024
  float* x4    = ws + 196608;         // 64x1024 (final x)
  float* fused = ws + 262144;         // 1024
  float* logit = ws + 263168;         // 64 (+pad to 270336)
  float* Pproj = ws + 270336;         // 16 x 64x1024 = 1M
  float* Pv    = ws + 1318912;        // 16 x 64x1024 = 1M
  float* Pat   = ws + 2367488;        // 16 x 64x1024 = 1M
  float* Ph    = ws + 3416064;        //  8 x 64x4096 = 2M
  float* Pf2   = ws + 5513216;        // 32 x 64x1024 = 2M
  float* Pa    = ws + 7610368;        //  8 x 64x4096 = 2M
  float* Pg    = ws + 9707520;        // 32 x 4096
  float* Po    = ws + 9838592;        // 64 x 4096

  const dim3 blk(256);

  // 1. proj partials: Pproj = concat(q,doc) @ Wp   (grid 16x16, Kt=128, K=2048)
  gemm_k<1><<<dim3(16,16), blk, 0, stream>>>(nullptr, nullptr, 0, 0, nullptr,
      q, doc, Wp, EDIM, Pproj, EDIM, 128);

  for (int l = 0; l < 2; ++l) {
    const float* Wv  = Wqkv + (size_t)l * EDIM * 3 * EDIM + 2 * EDIM;
    const float* bv  = bqkv + l * 3 * EDIM + 2 * EDIM;
    const float* Wol = Wo + (size_t)l * EDIM * EDIM;
    const float* W1l = W1 + (size_t)l * EDIM * FDIM;
    const float* W2l = W2 + (size_t)l * FDIM * EDIM;
    const float* xin = (l == 0) ? nullptr : x2;   // layer0 A comes from Pproj

    // 2/8. v partials: Pv = x @ Wv   (grid 16x16, Kt=64)
    if (l == 0)
      gemm_k<2><<<dim3(16,16), blk, 0, stream>>>(nullptr, Pproj, 16, EDIM, bp,
          nullptr, nullptr, Wv, 3 * EDIM, Pv, EDIM, 64);
    else
      gemm_k<0><<<dim3(16,16), blk, 0, stream>>>(xin, nullptr, 0, EDIM, nullptr,
          nullptr, nullptr, Wv, 3 * EDIM, Pv, EDIM, 64);

    // 3/9. attn partials: Pat = (psum Pv + bv) @ Wo   (grid 16x16, Kt=64)
    gemm_k<2><<<dim3(16,16), blk, 0, stream>>>(nullptr, Pv, 16, EDIM, bv,
        nullptr, nullptr, Wol, EDIM, Pat, EDIM, 64);

    // 4/10. LN1: x_out = LN(psum Pat + bo + residual)
    float* xo1 = (l == 0) ? x1 : x3;
    if (l == 0)
      ln_k<1><<<64, blk, 0, stream>>>(Pat, 16, bo + l * EDIM, nullptr,
          Pproj, 16, bp, ln1g + l * EDIM, ln1b + l * EDIM, xo1);
    else
      ln_k<0><<<64, blk, 0, stream>>>(Pat, 16, bo + l * EDIM, x2,
          nullptr, 0, nullptr, ln1g + l * EDIM, ln1b + l * EDIM, xo1);

    // 5/11. ffn1 partials: Ph = x @ W1   (grid 64x8, Kt=128)
    gemm_k<0><<<dim3(64,8), blk, 0, stream>>>(xo1, nullptr, 0, EDIM, nullptr,
        nullptr, nullptr, W1l, FDIM, Ph, FDIM, 128);

    // 6/12. ffn2 partials: Pf2 = relu(psum Ph + b1) @ W2   (grid 16x32, Kt=128)
    gemm_k<3><<<dim3(16,32), blk, 0, stream>>>(nullptr, Ph, 8, FDIM,
        b1 + (size_t)l * FDIM, nullptr, nullptr, W2l, EDIM, Pf2, EDIM, 128);

    // 7/13. LN2: x_out = LN(psum Pf2 + b2 + x)
    float* xo2 = (l == 0) ? x2 : x4;
    ln_k<0><<<64, blk, 0, stream>>>(Pf2, 32, b2 + l * EDIM, xo1,
        nullptr, 0, nullptr, ln2g + l * EDIM, ln2b + l * EDIM, xo2);
  }

  // 14. wa1 partials: Pa = x4 @ Wa1   (grid 64x8, Kt=128)
  gemm_k<0><<<dim3(64,8), blk, 0, stream>>>(x4, nullptr, 0, EDIM, nullptr,
      nullptr, nullptr, Wa1, FDIM, Pa, FDIM, 128);

  // 15-16. logits, softmax + pool
  logits_k<<<64, blk, 0, stream>>>(Pa, 8, ba1, Wa2, ba2, logit);
  pool_k<<<4, blk, 0, stream>>>(logit, x4, fused, out + FDIM);

  // 17-19. head GEMVs (float4/lane) + final
  gemv1_k<<<dim3(4,32), blk, 0, stream>>>(fused, Wf1, Pg);
  gemv2_k<<<dim3(4,64), blk, 0, stream>>>(Pg, 32, bf1, Wf2, Po);
  final_k<<<4, blk, 0, stream>>>(Po, 64, bf2, out);
}